// Round 6
// baseline (160.161 us; speedup 1.0000x reference)
//
#include <hip/hip_runtime.h>

// Regime-switching KF — PER-LANE SCALAR v3: TWO series per lane (scalar
// interleave), 128 series/wave, 128 waves. R5 post-mortem: all structures
// cluster at ~1700-1950 cyc/step regardless of inst count (290-600) —
// single-wave in-order issue with ILP~1.5 means ~2 stall cycles per inst;
// inst-count cuts just raise per-inst stall (v1 3.06 -> v2 3.87 cyc/inst).
// Fix: duplicate the whole per-series state and run TWO independent step
// DAGs in the same basic blocks; the scheduler interleaves them, pushing
// ILP toward ~3 and per-inst cost toward the 2-cyc issue floor. Unlike the
// R3 packed-pair failure this has no v_pk (half-rate on gfx950 per R3
// evidence) and no DPP. Algebra per series identical to v2:
// uy-restructure (u = uy - G e, input-only Y-block incl. branch-12),
// iM-late (SC = S*adj(M), 1/det folded into t/quad11/W11i),
// v2f regime-2 twin (kept identical to v2 for clean A/B).

typedef float v2f __attribute__((ext_vector_type(2)));
typedef v2f v2fu __attribute__((aligned(4)));

static __device__ __forceinline__ float frcp(float x)  { return __builtin_amdgcn_rcpf(x); }
static __device__ __forceinline__ float frsq(float x)  { return __builtin_amdgcn_rsqf(x); }
static __device__ __forceinline__ float fexp2(float x) { return __builtin_amdgcn_exp2f(x); }
static __device__ __forceinline__ float flog2(float x) { return __builtin_amdgcn_logf(x); }
static __device__ __forceinline__ v2f sp(float x) { return (v2f){x, x}; }
static __device__ __forceinline__ v2f rsq2(v2f a) { return (v2f){frsq(a.x), frsq(a.y)}; }

#define EPSF   1e-9f
#define L2E    1.4426950408889634f    // log2(e)
#define LN2    0.6931471805599453f
#define L2_2PI_9 23.86346461225016f   // 9*log2(2*pi)
#define C12F   1.00001e-4f            // (1 - 0.9999) + 1e-9
#define P22F   0.99990001f            // 0.9999 + 1e-9
#define QK     (-0.5f * L2E)

__global__ __launch_bounds__(64, 1)
void kf_kernel(const float* __restrict__ y,      // y[n][t][o]
               const float* __restrict__ pBG, const float* __restrict__ pBT,
               const float* __restrict__ pBB, const float* __restrict__ pBW,
               const float* __restrict__ lam1, const float* __restrict__ lam2,
               const float* __restrict__ qd,  const float* __restrict__ rd,
               const float* __restrict__ pG1, const float* __restrict__ pG2,
               float* __restrict__ partial, int N, int Nt)
{
    const int lane = threadIdx.x;
    const int base = blockIdx.x * 128;            // two series per lane
    const int sidA = base + lane;
    const int sidB = base + 64 + lane;
    const bool vA = (sidA < N), vB = (sidB < N);
    const int rowlen = Nt * 9;                    // 576

    // ---- wave-uniform setup ----
    const float bg = pBG[0], bt = pBT[0], bb = pBB[0], bw = pBW[0];
    const float a1 = lam1[0], a2 = lam1[1];
    const float a4 = lam1[2], a5 = lam1[3];
    const float a7 = lam1[4], a8 = lam1[5];
    float l2v[9], id[9], ld[9];
    l2v[0] = 1.f;
    #pragma unroll
    for (int i = 0; i < 8; ++i) l2v[i + 1] = lam2[i];
    float l2detD = 0.f;
    #pragma unroll
    for (int o = 0; o < 9; ++o) {
        float dv = fabsf(rd[o]) + 1.0e-4f + 1.0e-5f;   // R diag + jitter
        id[o] = 1.0f / dv;
        ld[o] = l2v[o] * id[o];
        l2detD += flog2(dv);
    }
    const float id8 = id[8], ld8 = ld[8];
    const v2f idv01 = {id[0], id[1]}, idv23 = {id[2], id[3]},
              idv45 = {id[4], id[5]}, idv67 = {id[6], id[7]};
    const v2f ldv01 = {ld[0], ld[1]}, ldv23 = {ld[2], ld[3]},
              ldv45 = {ld[4], ld[5]}, ldv67 = {ld[6], ld[7]};
    const float aid0 = id[0],    aid1 = a1*id[1], aid2 = a2*id[2];
    const float aid3 = id[3],    aid4 = a4*id[4], aid5 = a5*id[5];
    const float aid6 = id[6],    aid7 = a7*id[7], aid8 = a8*id[8];
    const float q0 = fabsf(qd[0]) + 1e-4f, q1 = fabsf(qd[1]) + 1e-4f;
    const float q2 = fabsf(qd[2]) + 1e-4f, q3 = fabsf(qd[3]) + 1e-4f;
    const float g0 = id[0] + a1*a1*id[1] + a2*a2*id[2];
    const float g1 = id[3] + a4*a4*id[4] + a5*a5*id[5];
    const float g2 = id[6] + a7*a7*id[7] + a8*a8*id[8];
    float h = 0.f;
    #pragma unroll
    for (int o = 0; o < 9; ++o) h += l2v[o] * ld[o];
    const float pk0 = q0 / (1.f + q0 * g0);
    const float pk1 = q1 / (1.f + q1 * g1);
    const float pk2 = q2 / (1.f + q2 * g2);
    const float C12D = C12F * frsq((1.f + q0*g0) * (1.f + q1*g1) * (1.f + q2*g2));
    const float gam1 = pG1[0], w0c = pG2[0], w1c = pG2[1], w2c = pG2[2];
    const float CC = -0.5f * (l2detD + L2_2PI_9);
    const float bg2 = bg*bg, bt2 = bt*bt, bb2 = bb*bb, bw2 = bw*bw;
    const float bgbt = bg*bt, bgbb = bg*bb, btbb = bt*bb;
    const v2f hv = {h, h};

    // ---- per-series state (two copies) ----
    struct St {
        float pf1, pf2;
        float se0, se1, se2;
        float p00, p01, p02, p11, p12, p22;
        float sm2, sp2, acc2;
    };
    auto initSt = [&](St& s) {
        s.pf1 = 0.99f + EPSF; s.pf2 = 0.01f + EPSF;
        s.se0 = 0.f; s.se1 = 0.f; s.se2 = 0.f;
        s.p00 = 1000.f; s.p01 = 0.f; s.p02 = 0.f;
        s.p11 = 1000.f; s.p12 = 0.f; s.p22 = 1000.f;
        s.sm2 = 0.f; s.sp2 = 1e-9f; s.acc2 = 0.f;
    };
    St st0, st1;
    initSt(st0); initSt(st1);

    struct Yr { v2f ab, cd, ef, gh; float i8; };
    struct YB { float uy0, uy1, uy2, yl, ydy, f0, f1, f2, q12e; };

    const char* row0 = (const char*)(y + (size_t)(vA ? sidA : 0) * rowlen);
    const char* row1 = (const char*)(y + (size_t)(vB ? sidB : 0) * rowlen);
    auto loadY = [&](Yr& r, const char* rowb, int t) {
        const char* p = rowb + t * 36;
        r.ab = *(const v2fu*)(p);
        r.cd = *(const v2fu*)(p + 8);
        r.ef = *(const v2fu*)(p + 16);
        r.gh = *(const v2fu*)(p + 24);
        r.i8 = *(const float*)(p + 32);
    };
    // pure function of the observation row -> freely schedulable filler
    auto computeYB = [&](const Yr& r) {
        YB o;
        v2f m0 = idv01*r.ab, m1 = idv23*r.cd, m2 = idv45*r.ef, m3 = idv67*r.gh;
        v2f yq = m0*r.ab + m1*r.cd + m2*r.ef + m3*r.gh;
        o.ydy = fmaf(id8*r.i8, r.i8, yq.x + yq.y);
        v2f la = ldv01*r.ab + ldv23*r.cd + ldv45*r.ef + ldv67*r.gh;
        o.yl = fmaf(ld8, r.i8, la.x + la.y);
        o.uy0 = fmaf(aid2, r.cd.x, fmaf(aid1, r.ab.y, aid0*r.ab.x));
        o.uy1 = fmaf(aid5, r.ef.y, fmaf(aid4, r.ef.x, aid3*r.cd.y));
        o.uy2 = fmaf(aid8, r.i8,   fmaf(aid7, r.gh.y, aid6*r.gh.x));
        o.f0 = pk0*o.uy0; o.f1 = pk1*o.uy1; o.f2 = pk2*o.uy2;
        o.q12e = QK * (o.ydy - (o.f0*o.uy0 + o.f1*o.uy1 + o.f2*o.uy2));
        return o;
    };

    auto step = [&](St& st, const YB& yb) {
        // HMM transition
        float logit = fmaf(w2c, st.se2, fmaf(w1c, st.se1, fmaf(w0c, st.se0, gam1)));
        float p11s = frcp(1.f + fexp2(-L2E * logit));
        float pp1 = st.pf1 * (p11s + EPSF);
        float pp2 = st.pf1 * (1.f - p11s + EPSF);

        // prediction (regime 1): S = B P B^T + Q (symmetric)
        float e0 = bg*st.se0, e1 = bt*st.se1, e2 = bb*st.se2;
        float s00 = fmaf(bg2, st.p00, q0), s11 = fmaf(bt2, st.p11, q1), s22 = fmaf(bb2, st.p22, q2);
        float s01 = bgbt*st.p01, s02 = bgbb*st.p02, s12 = btbb*st.p12;

        // u = uy - G e ; vdv = ydy - e.(uy+u)
        float u0 = fmaf(-g0, e0, yb.uy0);
        float u1 = fmaf(-g1, e1, yb.uy1);
        float u2 = fmaf(-g2, e2, yb.uy2);
        float vdv = yb.ydy - (e0*(yb.uy0+u0) + e1*(yb.uy1+u1) + e2*(yb.uy2+u2));

        // M = I + S*diag(g); cofactors; det; SC = S*adj(M) (iM folded late)
        float m00 = fmaf(s00, g0, 1.f), m11 = fmaf(s11, g1, 1.f), m22 = fmaf(s22, g2, 1.f);
        float m01 = s01*g1, m02 = s02*g2;
        float m10 = s01*g0, m20 = s02*g0;
        float m12 = s12*g2, m21 = s12*g1;
        float c00 = fmaf(m11, m22, -m12*m21);
        float c01 = fmaf(m12, m20, -m10*m22);
        float c02 = fmaf(m10, m21, -m11*m20);
        float c10 = fmaf(m02, m21, -m01*m22);
        float c11 = fmaf(m00, m22, -m02*m20);
        float c12 = fmaf(m01, m20, -m00*m21);
        float c20 = fmaf(m01, m12, -m02*m11);
        float c21 = fmaf(m02, m10, -m00*m12);
        float c22 = fmaf(m00, m11, -m01*m10);
        float det = fmaf(m02, c02, fmaf(m01, c01, m00*c00));   // >= 1
        float rs  = frsq(det);
        float iM  = rs * rs;                                   // 1/det
        float SC00 = fmaf(s02, c20, fmaf(s01, c10, s00*c00));
        float SC01 = fmaf(s02, c21, fmaf(s01, c11, s00*c01));
        float SC02 = fmaf(s02, c22, fmaf(s01, c12, s00*c02));
        float SC11 = fmaf(s12, c21, fmaf(s11, c11, s01*c01));
        float SC12 = fmaf(s12, c22, fmaf(s11, c12, s01*c02));
        float SC22 = fmaf(s22, c22, fmaf(s12, c12, s02*c02));

        // branch 11: n = SC u; quad11 = vdv - (u.n)/det; eu = e + n/det
        float n0 = fmaf(SC02, u2, fmaf(SC01, u1, SC00*u0));
        float n1 = fmaf(SC12, u2, fmaf(SC11, u1, SC01*u0));
        float n2 = fmaf(SC22, u2, fmaf(SC12, u1, SC02*u0));
        float un = fmaf(u2, n2, fmaf(u1, n1, u0*n0));
        float quad11 = fmaf(-iM, un, vdv);
        float eu0 = fmaf(iM, n0, e0), eu1 = fmaf(iM, n1, e1), eu2 = fmaf(iM, n2, e2);

        // regime-2 twin (packed a=branch21, b=branch22): Sherman-Morrison
        float seS = st.se0 + st.se1 + st.se2;
        float sPs = fmaf(2.f, (st.p01 + st.p02) + st.p12, (st.p00 + st.p11) + st.p22);
        v2f m2v; m2v.x = seS * (1.f/3.f);          m2v.y = bw * st.sm2;
        v2f pvv; pvv.x = fmaf(sPs, 1.f/9.f, q3);   pvv.y = fmaf(bw2, st.sp2, q3);
        v2f ylv = sp(yb.yl);
        v2f u1v = ylv - m2v*hv;
        v2f vdav = sp(yb.ydy) - m2v*(sp(2.f*yb.yl) - m2v*hv);
        v2f denv = sp(1.f) + pvv*hv;
        v2f rv  = rsq2(denv);
        v2f puv = pvv*(rv*rv);
        v2f pu1 = puv*u1v;
        v2f quadv = vdav - pu1*u1v;
        v2f euv = m2v + pu1;

        // mixing (log2 domain; det^(-1/2) via rs/rv factors; q12e precomputed)
        float q11e = QK*quad11;
        float q21e = QK*quadv.x, q22e = QK*quadv.y;
        float Mq = fmaxf(fmaxf(q11e, yb.q12e), fmaxf(q21e, q22e));
        float w11 = pp1*rs           * fexp2(q11e - Mq);
        float w12 = st.pf2*C12D      * fexp2(yb.q12e - Mq);
        float w21 = pp2*rv.x         * fexp2(q21e - Mq);
        float w22 = st.pf2*P22F*rv.y * fexp2(q22e - Mq);
        float pr1n = w11 + w12, pr2n = w21 + w22;
        float ssum = pr1n + pr2n;
        st.acc2 += Mq + flog2(ssum);
        float inv1 = frcp(fmaf(EPSF, ssum, pr1n));
        float inv2 = frcp(fmaf(EPSF, ssum, pr2n));
        float issum = frcp(ssum);
        float W11 = w11*inv1, W12 = w12*inv1;
        float W21 = w21*inv2, W22 = w22*inv2;
        st.pf1 = fmaf(pr1n, issum, EPSF);
        st.pf2 = fmaf(pr2n, issum, EPSF);
        float W11i = W11 * iM;                  // folds Ci = SC/det into collapse

        // collapse regime 1 (symmetric P; branch-12 posterior = diag(pk))
        float ne0 = fmaf(W12, yb.f0, W11*eu0);
        float ne1 = fmaf(W12, yb.f1, W11*eu1);
        float ne2 = fmaf(W12, yb.f2, W11*eu2);
        float da0 = eu0-ne0, da1 = eu1-ne1, da2 = eu2-ne2;
        float db0 = yb.f0-ne0, db1 = yb.f1-ne1, db2 = yb.f2-ne2;
        st.p00 = fmaf(W12, fmaf(db0, db0, pk0), fmaf(W11, da0*da0, W11i*SC00));
        st.p01 = fmaf(W12, db0*db1,             fmaf(W11, da0*da1, W11i*SC01));
        st.p02 = fmaf(W12, db0*db2,             fmaf(W11, da0*da2, W11i*SC02));
        st.p11 = fmaf(W12, fmaf(db1, db1, pk1), fmaf(W11, da1*da1, W11i*SC11));
        st.p12 = fmaf(W12, db1*db2,             fmaf(W11, da1*da2, W11i*SC12));
        st.p22 = fmaf(W12, fmaf(db2, db2, pk2), fmaf(W11, da2*da2, W11i*SC22));
        st.se0 = ne0; st.se1 = ne1; st.se2 = ne2;

        // collapse regime 2
        float nm2 = fmaf(W22, euv.y, W21*euv.x);
        v2f dcv = euv - sp(nm2);
        v2f tv = puv + dcv*dcv;
        st.sp2 = fmaf(W22, tv.y, W21*tv.x);
        st.sm2 = nm2;
    };

    // pipeline: loads for buffer X land one full step before computeYB(X);
    // the two series' step DAGs sit adjacent in the same basic blocks so the
    // scheduler interleaves them (the ILP the single-series version lacked).
    Yr A0, B0, A1, B1; YB ya0, yb0, ya1, yb1;
    loadY(A0, row0, 0); loadY(A1, row1, 0);
    loadY(B0, row0, 1); loadY(B1, row1, 1);
    ya0 = computeYB(A0); ya1 = computeYB(A1);
    for (int t = 0; t < Nt; t += 2) {
        step(st0, ya0);
        step(st1, ya1);
        yb0 = computeYB(B0); yb1 = computeYB(B1);
        if (t + 2 < Nt) { loadY(A0, row0, t + 2); loadY(A1, row1, t + 2); }
        step(st0, yb0);
        step(st1, yb1);
        if (t + 2 < Nt) { ya0 = computeYB(A0); ya1 = computeYB(A1); }
        if (t + 3 < Nt) { loadY(B0, row0, t + 3); loadY(B1, row1, t + 3); }
    }

    // two results per lane; wave-reduce; one partial per block (1 wave/block)
    float acc = 0.f;
    if (vA) acc += (st0.acc2 + (float)Nt * CC) * LN2;
    if (vB) acc += (st1.acc2 + (float)Nt * CC) * LN2;
    #pragma unroll
    for (int off = 32; off; off >>= 1) acc += __shfl_down(acc, off, 64);
    if (lane == 0) partial[blockIdx.x] = acc;
}

__global__ __launch_bounds__(64)
void reduce_k(const float* __restrict__ part, float* __restrict__ out, int nb)
{
    float s = 0.f;
    for (int i = threadIdx.x; i < nb; i += 64) s += part[i];
    #pragma unroll
    for (int off = 32; off; off >>= 1) s += __shfl_down(s, off, 64);
    if (threadIdx.x == 0) out[0] = s;
}

extern "C" void kernel_launch(void* const* d_in, const int* in_sizes, int n_in,
                              void* d_out, int out_size, void* d_ws, size_t ws_size,
                              hipStream_t stream)
{
    const float* y    = (const float*)d_in[0];
    const float* pBG  = (const float*)d_in[1];
    const float* pBT  = (const float*)d_in[2];
    const float* pBB  = (const float*)d_in[3];
    const float* pBW  = (const float*)d_in[4];
    const float* lam1 = (const float*)d_in[5];
    const float* lam2 = (const float*)d_in[6];
    const float* qd   = (const float*)d_in[7];
    const float* rd   = (const float*)d_in[8];
    const float* pG1  = (const float*)d_in[9];
    const float* pG2  = (const float*)d_in[10];

    const int total = in_sizes[0];
    const int Nt = 64, O = 9;
    const int N = total / (Nt * O);
    const int blocks = (N + 127) / 128;          // 2 series per lane

    float* partial = (float*)d_ws;
    kf_kernel<<<blocks, 64, 0, stream>>>(y, pBG, pBT, pBB, pBW, lam1, lam2,
                                         qd, rd, pG1, pG2, partial, N, Nt);
    reduce_k<<<1, 64, 0, stream>>>(partial, (float*)d_out, blocks);
}

// Round 8
// 125.711 us; speedup vs baseline: 1.2740x; 1.2740x over previous
//
#include <hip/hip_runtime.h>

// Regime-switching KF — R0 quad structure (best measured 44.6us) + ONLY the
// input-only Y-slab hoist. R7 post-mortem: bundling uy-fold + iM-late + tail
// hoists + masked-constant lane-3 NaN'd; iM-late's det-scaled intermediates
// (~1e27) and the loss of R0's explicit NaN-safe z3 masks are the suspects.
// This version: R0 verbatim (z3 masks, iM-early Ci, unmasked lane-3 junk
// state, identical mixing/collapse) with one verified change:
//   slab: uy = sum aO*iO*y (== R0's u12), f = pkS*uy, ydy, yl, q12e —
//   pure functions of the observation row, precomputed per 4-step chunk
//   between step4 calls (independent work fills step4's stall slots).
//   In-step: uJ = uy - gS*epJ; vdv = ydy - qsum(z3(epJ*(uy+uJ)))
//   (per-lane identity ydyP - epJ*(uy+uJ) = v.w verified by expansion).
// In-step qsums 8 -> 5; ~20 VALU ops off the serial chain.

typedef float v2f __attribute__((ext_vector_type(2)));

static __device__ __forceinline__ float frcp(float x)  { return __builtin_amdgcn_rcpf(x); }
static __device__ __forceinline__ float frsq(float x)  { return __builtin_amdgcn_rsqf(x); }
static __device__ __forceinline__ float fexp2(float x) { return __builtin_amdgcn_exp2f(x); }
static __device__ __forceinline__ float flog2(float x) { return __builtin_amdgcn_logf(x); }

template <int CTRL>
static __device__ __forceinline__ float dppf(float x) {
    int i = __float_as_int(x);
    i = __builtin_amdgcn_mov_dpp(i, CTRL, 0xF, 0xF, true);
    return __int_as_float(i);
}
#define ROTL 0xC9   // quad_perm [1,2,0,3]: lane j reads lane j+1 (mod 3)
#define ROTR 0xD2   // quad_perm [2,0,1,3]: lane j reads lane j+2
#define XOR1 0xB1   // quad_perm [1,0,3,2]
#define XOR2 0x4E   // quad_perm [2,3,0,1]

static __device__ __forceinline__ float qsum(float x) {   // sum over the quad
    x += dppf<XOR1>(x);
    x += dppf<XOR2>(x);
    return x;
}

#define EPSF   1e-9f
#define L2E    1.4426950408889634f    // log2(e)
#define LN2    0.6931471805599453f
#define L2_2PI_9 23.86346461225016f   // 9*log2(2*pi)
#define C12F   1.00001e-4f            // (1 - 0.9999) + 1e-9
#define P22F   0.99990001f            // 0.9999 + 1e-9
#define QK     (-0.5f * L2E)

__global__ __launch_bounds__(64, 1)
void kf_kernel(const float* __restrict__ y,      // y[n][t][o]
               const float* __restrict__ pBG, const float* __restrict__ pBT,
               const float* __restrict__ pBB, const float* __restrict__ pBW,
               const float* __restrict__ lam1, const float* __restrict__ lam2,
               const float* __restrict__ qd,  const float* __restrict__ rd,
               const float* __restrict__ pG1, const float* __restrict__ pG2,
               float* __restrict__ partial, int N, int Nt)
{
    const int lane = threadIdx.x;
    const int j    = lane & 3;                     // 0..2 = factor row; 3 = aux
    const int sid  = (blockIdx.x * 64 + lane) >> 2;
    const bool valid = (sid < N);
    const bool isRow = (j < 3);
    const int jj = isRow ? j : 0;
    const int rowlen = Nt * 9;                     // 576
    const int nchunk = Nt / 4;

    // ---- wave-uniform setup ----
    const float bg = pBG[0], bt = pBT[0], bb = pBB[0], bw = pBW[0];
    float a[9], l2v[9], id[9], ld[9];
    a[0] = 1.f; a[1] = lam1[0]; a[2] = lam1[1];
    a[3] = 1.f; a[4] = lam1[2]; a[5] = lam1[3];
    a[6] = 1.f; a[7] = lam1[4]; a[8] = lam1[5];
    l2v[0] = 1.f;
    #pragma unroll
    for (int i = 0; i < 8; ++i) l2v[i + 1] = lam2[i];
    float l2detD = 0.f;
    #pragma unroll
    for (int o = 0; o < 9; ++o) {
        float dv = fabsf(rd[o]) + 1.0e-4f + 1.0e-5f;   // R diag + jitter
        id[o] = 1.0f / dv;
        ld[o] = l2v[o] * id[o];
        l2detD += flog2(dv);
    }
    const float q0 = fabsf(qd[0]) + 1e-4f, q1 = fabsf(qd[1]) + 1e-4f;
    const float q2 = fabsf(qd[2]) + 1e-4f, q3 = fabsf(qd[3]) + 1e-4f;
    const float g0 = a[0]*a[0]*id[0] + a[1]*a[1]*id[1] + a[2]*a[2]*id[2];
    const float g1 = a[3]*a[3]*id[3] + a[4]*a[4]*id[4] + a[5]*a[5]*id[5];
    const float g2 = a[6]*a[6]*id[6] + a[7]*a[7]*id[7] + a[8]*a[8]*id[8];
    float h = 0.f;
    #pragma unroll
    for (int o = 0; o < 9; ++o) h += l2v[o] * ld[o];
    const float pk0 = q0 / (1.f + q0 * g0);
    const float pk1 = q1 / (1.f + q1 * g1);
    const float pk2 = q2 / (1.f + q2 * g2);
    const float C12D = C12F * frsq((1.f + q0*g0) * (1.f + q1*g1) * (1.f + q2*g2));
    const float gam1 = pG1[0], w0c = pG2[0], w1c = pG2[1], w2c = pG2[2];
    const float CC = -0.5f * (l2detD + L2_2PI_9);

    // ---- per-lane selected constants (jj = own factor / triplet index) ----
    auto sel3 = [&](float x0, float x1, float x2) {
        float r = (jj == 1) ? x1 : x0;
        return (jj == 2) ? x2 : r;
    };
    const float aO0 = sel3(a[0], a[3], a[6]), aO1 = sel3(a[1], a[4], a[7]), aO2 = sel3(a[2], a[5], a[8]);
    const float iO0 = sel3(id[0], id[3], id[6]), iO1 = sel3(id[1], id[4], id[7]), iO2 = sel3(id[2], id[5], id[8]);
    const float lO0 = sel3(ld[0], ld[3], ld[6]), lO1 = sel3(ld[1], ld[4], ld[7]), lO2 = sel3(ld[2], ld[5], ld[8]);
    const float bS = sel3(bg, bt, bb), bN = sel3(bt, bb, bg), bP = sel3(bb, bg, bt);
    const float gS = sel3(g0, g1, g2), gN = sel3(g1, g2, g0), gP = sel3(g2, g0, g1);
    const float qS = sel3(q0, q1, q2);
    const float pkS = sel3(pk0, pk1, pk2);
    const float wS = sel3(w0c, w1c, w2c);

    auto z3 = [&](float x) { return isRow ? x : 0.0f; };   // NaN-safe lane-3 mask

    // ---- state ----
    float pf1 = 0.99f + EPSF, pf2 = 0.01f + EPSF;          // dup
    float seJ = 0.f;                                       // eta1[j]
    float Pr0 = 1000.f, Pr1 = 0.f, Pr2 = 0.f;              // P row j (rel: j, j+1, j+2)
    float sm2 = 0.f, sp2 = 1e-9f;                          // dup
    float acc2 = 0.0f;

    // ---- staging: each lane reads its own 3-obs triplet per step ----
    const float* row = y + (size_t)(valid ? sid : 0) * rowlen + 3 * jj;
    float A[12], B[12];
    auto loadChunk = [&](float (&buf)[12], int c) {
        const float* p = row + c * 36;
        #pragma unroll
        for (int s = 0; s < 4; ++s) {
            buf[s*3+0] = p[s*9+0];
            buf[s*3+1] = p[s*9+1];
            buf[s*3+2] = p[s*9+2];
        }
    };
    loadChunk(A, 0);

    // input-only slab for a 4-step chunk: uy (== R0's u12), f = pkS*uy,
    // ydy, yl, q12e. Pure functions of the observation row; independent
    // DPP/VALU chains that the scheduler can pull into step4's stall slots.
    struct YB4 { float uy[4], f[4], ydy[4], yl[4], q12e[4]; };
    auto computeYB4 = [&](YB4& o, const float (&buf)[12]) {
        #pragma unroll
        for (int s = 0; s < 4; ++s) {
            const float y0 = buf[s*3+0], y1 = buf[s*3+1], y2 = buf[s*3+2];
            float w0 = iO0*y0, w1 = iO1*y1, w2 = iO2*y2;
            float uy = aO0*w0 + aO1*w1 + aO2*w2;
            float ydy = qsum(z3(w0*y0 + w1*y1 + w2*y2));
            float yl  = qsum(z3(lO0*y0 + lO1*y1 + lO2*y2));
            float f = pkS * uy;
            float q12 = qsum(z3(pkS * uy * uy));
            o.uy[s] = uy; o.f[s] = f; o.ydy[s] = ydy; o.yl[s] = yl;
            o.q12e[s] = QK * (ydy - q12);
        }
    };

    auto step4 = [&](const YB4& yb) {
        #pragma unroll
        for (int s = 0; s < 4; ++s) {
            const float uy = yb.uy[s], fJ = yb.f[s];
            const float ydy = yb.ydy[s], yl = yb.yl[s], q12e = yb.q12e[s];

            // HMM transition (logit allreduced; sigmoid dup)
            float logit = gam1 + qsum(z3(wS * seJ));
            float esig = fexp2(-logit * L2E);
            float p11 = frcp(1.f + esig);
            float pf11 = p11 + EPSF, pf21 = 1.f - p11 + EPSF;

            // prediction: mean comp j, S row j (relative), M row j
            float epJ = bS * seJ;
            float S0 = bS*bS*Pr0 + qS;
            float S1 = bS*bN*Pr1;
            float S2 = bS*bP*Pr2;
            float M0 = S0*gS + 1.f;
            float M1 = S1*gN;
            float M2 = S2*gP;

            // innovation via the uy-fold (identity: ydyP - epJ*(uy+uJ) = v.w)
            float uJ = uy - gS * epJ;
            float vdv = ydy - qsum(z3(epJ * (uy + uJ)));

            // 3x3: gather other M rows, cross-product cofactor row, local det
            float Mn0 = dppf<ROTL>(M0), Mn1 = dppf<ROTL>(M1), Mn2 = dppf<ROTL>(M2);
            float Mp0 = dppf<ROTR>(M0), Mp1 = dppf<ROTR>(M1), Mp2 = dppf<ROTR>(M2);
            float cf0 = Mn0*Mp0 - Mn1*Mp2;
            float cf1 = Mn1*Mp1 - Mn2*Mp0;
            float cf2 = Mn2*Mp2 - Mn0*Mp1;
            float det = M0*cf0 + M1*cf1 + M2*cf2;   // det(M) >= 1
            float rs  = frsq(det);
            float iM  = rs * rs;                    // 1/det
            float cn0 = dppf<ROTL>(cf0), cn1 = dppf<ROTL>(cf1), cn2 = dppf<ROTL>(cf2);
            float cp0 = dppf<ROTR>(cf0), cp1 = dppf<ROTR>(cf1), cp2 = dppf<ROTR>(cf2);
            // Ci row j = (S * cof) row j / det  (N = S*cof symmetric)
            float Ci0 = iM * (S0*cf0 + S1*cn2 + S2*cp1);
            float Ci1 = iM * (S0*cf1 + S1*cn0 + S2*cp2);
            float Ci2 = iM * (S0*cf2 + S1*cn1 + S2*cp0);

            // t = Ci u ; quad11
            float uN = dppf<ROTL>(uJ), uP = dppf<ROTR>(uJ);
            float tJ = Ci0*uJ + Ci1*uN + Ci2*uP;
            float quad11 = vdv - qsum(z3(uJ * tJ));
            float euJ = epJ + tJ;

            // regime-2 twin (duplicated): rank-1 Sherman-Morrison, branches 21/22
            float seS = qsum(z3(seJ));
            float sP  = qsum(z3(Pr0 + Pr1 + Pr2));
            v2f m2v; m2v.x = seS * (1.f/3.f);       m2v.y = bw * sm2;
            v2f pvv; pvv.x = q3 + sP * (1.f/9.f);   pvv.y = bw*bw*sp2 + q3;
            v2f u1v  = (v2f){yl, yl} - m2v * (v2f){h, h};
            v2f vdav = (v2f){ydy, ydy} - m2v * ((v2f){2.f*yl, 2.f*yl} - m2v * (v2f){h, h});
            v2f denv = (v2f){1.f, 1.f} + pvv * (v2f){h, h};
            v2f rvv; rvv.x = frsq(denv.x); rvv.y = frsq(denv.y);
            v2f idev = rvv * rvv;
            v2f puv = pvv * idev;
            v2f quadv = vdav - puv * u1v * u1v;
            v2f euv = m2v + puv * u1v;

            // mixing (dup; dets folded via rsq factors; q12e precomputed)
            float q11e = QK * quad11;
            float q21e = QK * quadv.x, q22e = QK * quadv.y;
            float Mq = fmaxf(fmaxf(q11e, q12e), fmaxf(q21e, q22e));
            float w11 = pf1 * pf11 * rs    * fexp2(q11e - Mq);
            float w12 = pf2 * C12D         * fexp2(q12e - Mq);
            float w21 = pf1 * pf21 * rvv.x * fexp2(q21e - Mq);
            float w22 = pf2 * P22F * rvv.y * fexp2(q22e - Mq);
            float ssum = w11 + w12 + w21 + w22;
            acc2 += Mq + flog2(ssum);
            float pr1n = w11 + w12, pr2n = w21 + w22;
            float den1 = pr1n + EPSF * ssum, den2 = pr2n + EPSF * ssum;
            float inv1 = frcp(den1), inv2 = frcp(den2), issum = frcp(ssum);
            float W11 = w11*inv1, W12 = w12*inv1;
            float W21 = w21*inv2, W22 = w22*inv2;
            pf1 = pr1n * issum + EPSF;
            pf2 = pr2n * issum + EPSF;

            // collapse regime 1 (row form)
            float neJ = W11*euJ + W12*fJ;
            float daJ = euJ - neJ, dbJ = fJ - neJ;
            float daN = dppf<ROTL>(daJ), daP = dppf<ROTR>(daJ);
            float dbN = dppf<ROTL>(dbJ), dbP = dppf<ROTR>(dbJ);
            Pr0 = W11*(Ci0 + daJ*daJ) + W12*(pkS + dbJ*dbJ);
            Pr1 = W11*(Ci1 + daJ*daN) + W12*(dbJ*dbN);
            Pr2 = W11*(Ci2 + daJ*daP) + W12*(dbJ*dbP);
            seJ = neJ;

            // collapse regime 2 (dup)
            float nm2 = W21*euv.x + W22*euv.y;
            float dc = euv.x - nm2, dd = euv.y - nm2;
            sp2 = W21*(puv.x + dc*dc) + W22*(puv.y + dd*dd);
            sm2 = nm2;
        }
    };

    YB4 ya, yb;
    computeYB4(ya, A);
    for (int c = 0; c < nchunk; c += 2) {
        if (c + 1 < nchunk) loadChunk(B, c + 1);
        step4(ya);
        if (c + 1 < nchunk) computeYB4(yb, B);
        if (c + 2 < nchunk) loadChunk(A, c + 2);
        if (c + 1 < nchunk) step4(yb);
        if (c + 2 < nchunk) computeYB4(ya, A);
    }

    // one result per series (sublane 0), wave-reduce, one partial per block
    float acc = (valid && j == 0) ? (acc2 + (float)Nt * CC) * LN2 : 0.0f;
    #pragma unroll
    for (int off = 32; off; off >>= 1) acc += __shfl_down(acc, off, 64);
    if (lane == 0) partial[blockIdx.x] = acc;
}

__global__ __launch_bounds__(64)
void reduce_k(const float* __restrict__ part, float* __restrict__ out, int nb)
{
    float s = 0.f;
    for (int i = threadIdx.x; i < nb; i += 64) s += part[i];
    #pragma unroll
    for (int off = 32; off; off >>= 1) s += __shfl_down(s, off, 64);
    if (threadIdx.x == 0) out[0] = s;
}

extern "C" void kernel_launch(void* const* d_in, const int* in_sizes, int n_in,
                              void* d_out, int out_size, void* d_ws, size_t ws_size,
                              hipStream_t stream)
{
    const float* y    = (const float*)d_in[0];
    const float* pBG  = (const float*)d_in[1];
    const float* pBT  = (const float*)d_in[2];
    const float* pBB  = (const float*)d_in[3];
    const float* pBW  = (const float*)d_in[4];
    const float* lam1 = (const float*)d_in[5];
    const float* lam2 = (const float*)d_in[6];
    const float* qd   = (const float*)d_in[7];
    const float* rd   = (const float*)d_in[8];
    const float* pG1  = (const float*)d_in[9];
    const float* pG2  = (const float*)d_in[10];

    const int total = in_sizes[0];
    const int Nt = 64, O = 9;
    const int N = total / (Nt * O);
    const int blocks = (N * 4 + 63) / 64;    // 4 lanes per series

    float* partial = (float*)d_ws;
    kf_kernel<<<blocks, 64, 0, stream>>>(y, pBG, pBT, pBB, pBW, lam1, lam2,
                                         qd, rd, pG1, pG2, partial, N, Nt);
    reduce_k<<<1, 64, 0, stream>>>(partial, (float*)d_out, blocks);
}

// Round 9
// 124.828 us; speedup vs baseline: 1.2831x; 1.0071x over previous
//
#include <hip/hip_runtime.h>

// Regime-switching KF — R8 (quad + Y-slab, 42.8us) + z3-MASKED tail hoists.
// R7's NaN is now explained: its tail hoists read lane-3 junk state via
// UNMASKED qsum(seJ); the safety invariant of this family is "nothing read
// from lane 3 escapes" (all qsums z3-masked, acc read at j==0 only).
// This version hoists every state-only chain to the step tail WITH z3:
//   - HMM sigmoid: qsum(z3(wS*seJ)) -> exp2 -> rcp -> pp1h/pp2h
//   - twin priors: seS/sP qsums, m2v/pvv/denv -> rsq x2 -> puv, and the
//     mixing coefficients w21h/w22h/c12h
// so they overlap with the collapse + next slab instead of serializing at
// the step front. In-step qsums 5 -> 2 (vdv, quad11); exp2/rcp/rsq off the
// front chain. Hoisted values provably equal what the next step would
// compute (they reduce exactly the carried state). Rest is R8 verbatim.

typedef float v2f __attribute__((ext_vector_type(2)));

static __device__ __forceinline__ float frcp(float x)  { return __builtin_amdgcn_rcpf(x); }
static __device__ __forceinline__ float frsq(float x)  { return __builtin_amdgcn_rsqf(x); }
static __device__ __forceinline__ float fexp2(float x) { return __builtin_amdgcn_exp2f(x); }
static __device__ __forceinline__ float flog2(float x) { return __builtin_amdgcn_logf(x); }

template <int CTRL>
static __device__ __forceinline__ float dppf(float x) {
    int i = __float_as_int(x);
    i = __builtin_amdgcn_mov_dpp(i, CTRL, 0xF, 0xF, true);
    return __int_as_float(i);
}
#define ROTL 0xC9   // quad_perm [1,2,0,3]: lane j reads lane j+1 (mod 3)
#define ROTR 0xD2   // quad_perm [2,0,1,3]: lane j reads lane j+2
#define XOR1 0xB1   // quad_perm [1,0,3,2]
#define XOR2 0x4E   // quad_perm [2,3,0,1]

static __device__ __forceinline__ float qsum(float x) {   // sum over the quad
    x += dppf<XOR1>(x);
    x += dppf<XOR2>(x);
    return x;
}

#define EPSF   1e-9f
#define L2E    1.4426950408889634f    // log2(e)
#define LN2    0.6931471805599453f
#define L2_2PI_9 23.86346461225016f   // 9*log2(2*pi)
#define C12F   1.00001e-4f            // (1 - 0.9999) + 1e-9
#define P22F   0.99990001f            // 0.9999 + 1e-9
#define QK     (-0.5f * L2E)

__global__ __launch_bounds__(64, 1)
void kf_kernel(const float* __restrict__ y,      // y[n][t][o]
               const float* __restrict__ pBG, const float* __restrict__ pBT,
               const float* __restrict__ pBB, const float* __restrict__ pBW,
               const float* __restrict__ lam1, const float* __restrict__ lam2,
               const float* __restrict__ qd,  const float* __restrict__ rd,
               const float* __restrict__ pG1, const float* __restrict__ pG2,
               float* __restrict__ partial, int N, int Nt)
{
    const int lane = threadIdx.x;
    const int j    = lane & 3;                     // 0..2 = factor row; 3 = aux
    const int sid  = (blockIdx.x * 64 + lane) >> 2;
    const bool valid = (sid < N);
    const bool isRow = (j < 3);
    const int jj = isRow ? j : 0;
    const int rowlen = Nt * 9;                     // 576
    const int nchunk = Nt / 4;

    // ---- wave-uniform setup ----
    const float bg = pBG[0], bt = pBT[0], bb = pBB[0], bw = pBW[0];
    float a[9], l2v[9], id[9], ld[9];
    a[0] = 1.f; a[1] = lam1[0]; a[2] = lam1[1];
    a[3] = 1.f; a[4] = lam1[2]; a[5] = lam1[3];
    a[6] = 1.f; a[7] = lam1[4]; a[8] = lam1[5];
    l2v[0] = 1.f;
    #pragma unroll
    for (int i = 0; i < 8; ++i) l2v[i + 1] = lam2[i];
    float l2detD = 0.f;
    #pragma unroll
    for (int o = 0; o < 9; ++o) {
        float dv = fabsf(rd[o]) + 1.0e-4f + 1.0e-5f;   // R diag + jitter
        id[o] = 1.0f / dv;
        ld[o] = l2v[o] * id[o];
        l2detD += flog2(dv);
    }
    const float q0 = fabsf(qd[0]) + 1e-4f, q1 = fabsf(qd[1]) + 1e-4f;
    const float q2 = fabsf(qd[2]) + 1e-4f, q3 = fabsf(qd[3]) + 1e-4f;
    const float g0 = a[0]*a[0]*id[0] + a[1]*a[1]*id[1] + a[2]*a[2]*id[2];
    const float g1 = a[3]*a[3]*id[3] + a[4]*a[4]*id[4] + a[5]*a[5]*id[5];
    const float g2 = a[6]*a[6]*id[6] + a[7]*a[7]*id[7] + a[8]*a[8]*id[8];
    float h = 0.f;
    #pragma unroll
    for (int o = 0; o < 9; ++o) h += l2v[o] * ld[o];
    const float pk0 = q0 / (1.f + q0 * g0);
    const float pk1 = q1 / (1.f + q1 * g1);
    const float pk2 = q2 / (1.f + q2 * g2);
    const float C12D = C12F * frsq((1.f + q0*g0) * (1.f + q1*g1) * (1.f + q2*g2));
    const float gam1 = pG1[0], w0c = pG2[0], w1c = pG2[1], w2c = pG2[2];
    const float CC = -0.5f * (l2detD + L2_2PI_9);
    const float bw2 = bw * bw;

    // ---- per-lane selected constants (jj = own factor / triplet index) ----
    auto sel3 = [&](float x0, float x1, float x2) {
        float r = (jj == 1) ? x1 : x0;
        return (jj == 2) ? x2 : r;
    };
    const float aO0 = sel3(a[0], a[3], a[6]), aO1 = sel3(a[1], a[4], a[7]), aO2 = sel3(a[2], a[5], a[8]);
    const float iO0 = sel3(id[0], id[3], id[6]), iO1 = sel3(id[1], id[4], id[7]), iO2 = sel3(id[2], id[5], id[8]);
    const float lO0 = sel3(ld[0], ld[3], ld[6]), lO1 = sel3(ld[1], ld[4], ld[7]), lO2 = sel3(ld[2], ld[5], ld[8]);
    const float bS = sel3(bg, bt, bb), bN = sel3(bt, bb, bg), bP = sel3(bb, bg, bt);
    const float gS = sel3(g0, g1, g2), gN = sel3(g1, g2, g0), gP = sel3(g2, g0, g1);
    const float qS = sel3(q0, q1, q2);
    const float pkS = sel3(pk0, pk1, pk2);
    const float wS = sel3(w0c, w1c, w2c);

    auto z3 = [&](float x) { return isRow ? x : 0.0f; };   // NaN-safe lane-3 mask

    // ---- state ----
    float pf1 = 0.99f + EPSF, pf2 = 0.01f + EPSF;          // dup
    float seJ = 0.f;                                       // eta1[j]
    float Pr0 = 1000.f, Pr1 = 0.f, Pr2 = 0.f;              // P row j (rel: j, j+1, j+2)
    float sm2 = 0.f, sp2 = 1e-9f;                          // dup
    float acc2 = 0.0f;

    // ---- hoisted state-only quantities (recomputed at each step's tail) ----
    float pp1h, pp2h, w21h, w22h, c12h;
    v2f m2h, puh;
    auto hoist = [&]() {
        float logit = gam1 + qsum(z3(wS * seJ));
        float esig = fexp2(-logit * L2E);
        float p11 = frcp(1.f + esig);
        pp1h = pf1 * (p11 + EPSF);
        float pp2 = pf1 * (1.f - p11 + EPSF);
        float seS = qsum(z3(seJ));
        float sP  = qsum(z3(Pr0 + Pr1 + Pr2));
        m2h.x = seS * (1.f/3.f);
        m2h.y = bw * sm2;
        v2f pvv; pvv.x = q3 + sP * (1.f/9.f); pvv.y = bw2*sp2 + q3;
        v2f rvv; rvv.x = frsq(1.f + pvv.x*h); rvv.y = frsq(1.f + pvv.y*h);
        puh = pvv * (rvv * rvv);
        w21h = pp2 * rvv.x;
        w22h = (pf2 * P22F) * rvv.y;
        c12h = pf2 * C12D;
    };

    // ---- staging: each lane reads its own 3-obs triplet per step ----
    const float* row = y + (size_t)(valid ? sid : 0) * rowlen + 3 * jj;
    float A[12], B[12];
    auto loadChunk = [&](float (&buf)[12], int c) {
        const float* p = row + c * 36;
        #pragma unroll
        for (int s = 0; s < 4; ++s) {
            buf[s*3+0] = p[s*9+0];
            buf[s*3+1] = p[s*9+1];
            buf[s*3+2] = p[s*9+2];
        }
    };
    loadChunk(A, 0);

    // input-only slab for a 4-step chunk: uy (== R0's u12), f = pkS*uy,
    // ydy, yl, q12e. Pure functions of the observation row; independent
    // DPP/VALU chains that the scheduler can pull into step4's stall slots.
    struct YB4 { float uy[4], f[4], ydy[4], yl[4], q12e[4]; };
    auto computeYB4 = [&](YB4& o, const float (&buf)[12]) {
        #pragma unroll
        for (int s = 0; s < 4; ++s) {
            const float y0 = buf[s*3+0], y1 = buf[s*3+1], y2 = buf[s*3+2];
            float w0 = iO0*y0, w1 = iO1*y1, w2 = iO2*y2;
            float uy = aO0*w0 + aO1*w1 + aO2*w2;
            float ydy = qsum(z3(w0*y0 + w1*y1 + w2*y2));
            float yl  = qsum(z3(lO0*y0 + lO1*y1 + lO2*y2));
            float f = pkS * uy;
            float q12 = qsum(z3(pkS * uy * uy));
            o.uy[s] = uy; o.f[s] = f; o.ydy[s] = ydy; o.yl[s] = yl;
            o.q12e[s] = QK * (ydy - q12);
        }
    };

    auto step4 = [&](const YB4& yb) {
        #pragma unroll
        for (int s = 0; s < 4; ++s) {
            const float uy = yb.uy[s], fJ = yb.f[s];
            const float ydy = yb.ydy[s], yl = yb.yl[s], q12e = yb.q12e[s];

            // prediction: mean comp j, S row j (relative), M row j
            float epJ = bS * seJ;
            float S0 = bS*bS*Pr0 + qS;
            float S1 = bS*bN*Pr1;
            float S2 = bS*bP*Pr2;
            float M0 = S0*gS + 1.f;
            float M1 = S1*gN;
            float M2 = S2*gP;

            // innovation via the uy-fold (identity: ydyP - epJ*(uy+uJ) = v.w)
            float uJ = uy - gS * epJ;
            float vdv = ydy - qsum(z3(epJ * (uy + uJ)));

            // 3x3: gather other M rows, cross-product cofactor row, local det
            float Mn0 = dppf<ROTL>(M0), Mn1 = dppf<ROTL>(M1), Mn2 = dppf<ROTL>(M2);
            float Mp0 = dppf<ROTR>(M0), Mp1 = dppf<ROTR>(M1), Mp2 = dppf<ROTR>(M2);
            float cf0 = Mn0*Mp0 - Mn1*Mp2;
            float cf1 = Mn1*Mp1 - Mn2*Mp0;
            float cf2 = Mn2*Mp2 - Mn0*Mp1;
            float det = M0*cf0 + M1*cf1 + M2*cf2;   // det(M) >= 1
            float rs  = frsq(det);
            float iM  = rs * rs;                    // 1/det
            float cn0 = dppf<ROTL>(cf0), cn1 = dppf<ROTL>(cf1), cn2 = dppf<ROTL>(cf2);
            float cp0 = dppf<ROTR>(cf0), cp1 = dppf<ROTR>(cf1), cp2 = dppf<ROTR>(cf2);
            // Ci row j = (S * cof) row j / det  (N = S*cof symmetric)
            float Ci0 = iM * (S0*cf0 + S1*cn2 + S2*cp1);
            float Ci1 = iM * (S0*cf1 + S1*cn0 + S2*cp2);
            float Ci2 = iM * (S0*cf2 + S1*cn1 + S2*cp0);

            // t = Ci u ; quad11
            float uN = dppf<ROTL>(uJ), uP = dppf<ROTR>(uJ);
            float tJ = Ci0*uJ + Ci1*uN + Ci2*uP;
            float quad11 = vdv - qsum(z3(uJ * tJ));
            float euJ = epJ + tJ;

            // regime-2 twin likelihood part (priors m2h/puh hoisted)
            v2f u1v  = (v2f){yl, yl} - m2h * (v2f){h, h};
            v2f vdav = (v2f){ydy, ydy} - m2h * ((v2f){2.f*yl, 2.f*yl} - m2h * (v2f){h, h});
            v2f pu1 = puh * u1v;
            v2f quadv = vdav - pu1 * u1v;
            v2f euv = m2h + pu1;

            // mixing (dup; dets folded via hoisted rvv factors; q12e precomputed)
            float q11e = QK * quad11;
            float q21e = QK * quadv.x, q22e = QK * quadv.y;
            float Mq = fmaxf(fmaxf(q11e, q12e), fmaxf(q21e, q22e));
            float w11 = pp1h * rs * fexp2(q11e - Mq);
            float w12 = c12h      * fexp2(q12e - Mq);
            float w21 = w21h      * fexp2(q21e - Mq);
            float w22 = w22h      * fexp2(q22e - Mq);
            float ssum = w11 + w12 + w21 + w22;
            acc2 += Mq + flog2(ssum);
            float pr1n = w11 + w12, pr2n = w21 + w22;
            float den1 = pr1n + EPSF * ssum, den2 = pr2n + EPSF * ssum;
            float inv1 = frcp(den1), inv2 = frcp(den2), issum = frcp(ssum);
            float W11 = w11*inv1, W12 = w12*inv1;
            float W21 = w21*inv2, W22 = w22*inv2;
            pf1 = pr1n * issum + EPSF;
            pf2 = pr2n * issum + EPSF;

            // collapse regime 1 (row form)
            float neJ = W11*euJ + W12*fJ;
            float daJ = euJ - neJ, dbJ = fJ - neJ;
            float daN = dppf<ROTL>(daJ), daP = dppf<ROTR>(daJ);
            float dbN = dppf<ROTL>(dbJ), dbP = dppf<ROTR>(dbJ);
            Pr0 = W11*(Ci0 + daJ*daJ) + W12*(pkS + dbJ*dbJ);
            Pr1 = W11*(Ci1 + daJ*daN) + W12*(dbJ*dbN);
            Pr2 = W11*(Ci2 + daJ*daP) + W12*(dbJ*dbP);
            seJ = neJ;

            // collapse regime 2 (dup)
            float nm2 = W21*euv.x + W22*euv.y;
            float dc = euv.x - nm2, dd = euv.y - nm2;
            sp2 = W21*(puh.x + dc*dc) + W22*(puh.y + dd*dd);
            sm2 = nm2;

            // tail: recompute all state-only hoisted quantities (z3-masked)
            hoist();
        }
    };

    hoist();                                   // initial-state hoist
    YB4 ya, yb;
    computeYB4(ya, A);
    for (int c = 0; c < nchunk; c += 2) {
        if (c + 1 < nchunk) loadChunk(B, c + 1);
        step4(ya);
        if (c + 1 < nchunk) computeYB4(yb, B);
        if (c + 2 < nchunk) loadChunk(A, c + 2);
        if (c + 1 < nchunk) step4(yb);
        if (c + 2 < nchunk) computeYB4(ya, A);
    }

    // one result per series (sublane 0), wave-reduce, one partial per block
    float acc = (valid && j == 0) ? (acc2 + (float)Nt * CC) * LN2 : 0.0f;
    #pragma unroll
    for (int off = 32; off; off >>= 1) acc += __shfl_down(acc, off, 64);
    if (lane == 0) partial[blockIdx.x] = acc;
}

__global__ __launch_bounds__(64)
void reduce_k(const float* __restrict__ part, float* __restrict__ out, int nb)
{
    float s = 0.f;
    for (int i = threadIdx.x; i < nb; i += 64) s += part[i];
    #pragma unroll
    for (int off = 32; off; off >>= 1) s += __shfl_down(s, off, 64);
    if (threadIdx.x == 0) out[0] = s;
}

extern "C" void kernel_launch(void* const* d_in, const int* in_sizes, int n_in,
                              void* d_out, int out_size, void* d_ws, size_t ws_size,
                              hipStream_t stream)
{
    const float* y    = (const float*)d_in[0];
    const float* pBG  = (const float*)d_in[1];
    const float* pBT  = (const float*)d_in[2];
    const float* pBB  = (const float*)d_in[3];
    const float* pBW  = (const float*)d_in[4];
    const float* lam1 = (const float*)d_in[5];
    const float* lam2 = (const float*)d_in[6];
    const float* qd   = (const float*)d_in[7];
    const float* rd   = (const float*)d_in[8];
    const float* pG1  = (const float*)d_in[9];
    const float* pG2  = (const float*)d_in[10];

    const int total = in_sizes[0];
    const int Nt = 64, O = 9;
    const int N = total / (Nt * O);
    const int blocks = (N * 4 + 63) / 64;    // 4 lanes per series

    float* partial = (float*)d_ws;
    kf_kernel<<<blocks, 64, 0, stream>>>(y, pBG, pBT, pBB, pBW, lam1, lam2,
                                         qd, rd, pG1, pG2, partial, N, Nt);
    reduce_k<<<1, 64, 0, stream>>>(partial, (float*)d_out, blocks);
}